// Round 1
// 170.598 us; speedup vs baseline: 1.0035x; 1.0035x over previous
//
#include <hip/hip_runtime.h>
#include <math.h>

#define Bc 4
#define Vc 4
#define Hc 256
#define Wc 384
#define HWc (Hc*Wc)               // 98304
#define TOTc (Bc*Vc*HWc)          // 1572864
#define SCALE_MIN_c 1e-05f
#define SCALE_MAX_c 30.0f
#define EPS_c 1e-08f

// Output section offsets (in floats)
#define MEANS_OFF  ((size_t)0)
#define SCALES_OFF ((size_t)TOTc*3)
#define ROT_OFF    ((size_t)TOTc*6)
#define HARM_OFF   ((size_t)TOTc*10)
#define OPAC_OFF   ((size_t)TOTc*13)

__device__ __forceinline__ void async_copy16(const float4* g, float4* l) {
    __builtin_amdgcn_global_load_lds(
        (const __attribute__((address_space(1))) void*)g,
        (__attribute__((address_space(3))) void*)l,
        16, 0, 0);
}

__global__ __launch_bounds__(256, 6) void ga_kernel(
    const float* __restrict__ ext,    // (B,V,4,4)
    const float* __restrict__ intr,   // (B,V,3,3)
    const float* __restrict__ depths, // (B,V,H,W)
    const float* __restrict__ opac,   // (B,V,H,W)
    const float* __restrict__ raw,    // (B,V,H,W,12)
    float* __restrict__ out)
{
    // 12 KB only. Wave w exclusively owns float4 range [192w, 192w+192):
    // DMA-staged there, consumed there, then re-used as per-thread output
    // staging slots (12 floats/thread: [m0 m1 m2 | s0 s1 s2 | h0 h1 h2 | pad]).
    // No data ever crosses a wave boundary -> ZERO __syncthreads in this kernel.
    __shared__ float4 sRaw[768];

    const int tid  = threadIdx.x;
    const int lane = tid & 63;
    const int wv   = tid >> 6;          // wave id 0..3 (wave-uniform)
    const int g    = blockIdx.x * 256 + tid;

    // ---- per-wave async staging: each wave DMAs its own 3 KB region ----
    {
        const float4* gbase = reinterpret_cast<const float4*>(raw)
                            + (size_t)blockIdx.x * 768 + wv * 192;
        float4* lbase = &sRaw[wv * 192];          // wave-uniform LDS base
        async_copy16(gbase +   0 + lane, lbase +   0);   // HW adds lane*16
        async_copy16(gbase +  64 + lane, lbase +  64);
        async_copy16(gbase + 128 + lane, lbase + 128);
    }

    // coalesced scalar loads (in flight with the DMA + constants compute)
    const float dep = depths[g];
    const float op  = opac[g];

    // ---- per-view constants, computed redundantly per thread ----
    // Wave-uniform (view depends only on blockIdx), branchless, no arrays,
    // op-for-op identical to the previous tid==0 path -> bit-identical output.
    const int view = blockIdx.x / (HWc / 256);   // 0..15
    const float* E = ext  + view * 16;
    const float* I = intr + view * 9;

    // Rc2w = Rw2c^T
    const float R0 = E[0], R1 = E[4], R2 = E[8];
    const float R3 = E[1], R4 = E[5], R5 = E[9];
    const float R6 = E[2], R7 = E[6], R8 = E[10];
    const float t0 = E[3], t1 = E[7], t2 = E[11];
    const float O0 = -(R0*t0 + R1*t1 + R2*t2);
    const float O1 = -(R3*t0 + R4*t1 + R5*t2);
    const float O2 = -(R6*t0 + R7*t1 + R8*t2);

    // normalized intrinsics and its inverse
    const float a00 = I[0]*(1.0f/Wc), a01 = I[1]*(1.0f/Wc), a02 = I[2]*(1.0f/Wc);
    const float a10 = I[3]*(1.0f/Hc), a11 = I[4]*(1.0f/Hc), a12 = I[5]*(1.0f/Hc);
    const float a20 = I[6],           a21 = I[7],           a22 = I[8];
    const float det = a00*(a11*a22 - a12*a21)
                    - a01*(a10*a22 - a12*a20)
                    + a02*(a10*a21 - a11*a20);
    const float id = 1.0f / det;
    const float K0 = (a11*a22 - a12*a21)*id;
    const float K1 = (a02*a21 - a01*a22)*id;
    const float K2 = (a01*a12 - a02*a11)*id;
    const float K3 = (a12*a20 - a10*a22)*id;
    const float K4 = (a00*a22 - a02*a20)*id;
    const float K5 = (a02*a10 - a00*a12)*id;
    const float K6 = (a10*a21 - a11*a20)*id;
    const float K7 = (a01*a20 - a00*a21)*id;
    const float K8 = (a00*a11 - a01*a10)*id;

    const float det2 = a00*a11 - a01*a10;
    const float mult = 0.1f * ((a11*(1.0f/Wc) - a01*(1.0f/Hc))
                             + (-a10*(1.0f/Wc) + a00*(1.0f/Hc))) / det2;

    // c2w quaternion from Rc2w (branchless argmax selection, no local arrays)
    const float m00 = R0, m01 = R1, m02 = R2;
    const float m10 = R3, m11 = R4, m12 = R5;
    const float m20 = R6, m21 = R7, m22 = R8;
    const float qa0 = sqrtf(fmaxf(0.0f, 1.0f + m00 + m11 + m22));
    const float qa1 = sqrtf(fmaxf(0.0f, 1.0f + m00 - m11 - m22));
    const float qa2 = sqrtf(fmaxf(0.0f, 1.0f - m00 + m11 - m22));
    const float qa3 = sqrtf(fmaxf(0.0f, 1.0f - m00 - m11 + m22));
    float bq = qa0;
    float b0 = qa0*qa0, b1 = m21 - m12, b2 = m02 - m20, b3 = m10 - m01;
    {
        const bool s1 = qa1 > bq;
        b0 = s1 ? (m21 - m12) : b0;
        b1 = s1 ? (qa1*qa1)   : b1;
        b2 = s1 ? (m10 + m01) : b2;
        b3 = s1 ? (m02 + m20) : b3;
        bq = s1 ? qa1 : bq;
        const bool s2 = qa2 > bq;
        b0 = s2 ? (m02 - m20) : b0;
        b1 = s2 ? (m10 + m01) : b1;
        b2 = s2 ? (qa2*qa2)   : b2;
        b3 = s2 ? (m12 + m21) : b3;
        bq = s2 ? qa2 : bq;
        const bool s3 = qa3 > bq;
        b0 = s3 ? (m10 - m01) : b0;
        b1 = s3 ? (m20 + m02) : b1;
        b2 = s3 ? (m21 + m12) : b2;
        b3 = s3 ? (qa3*qa3)   : b3;
        bq = s3 ? qa3 : bq;
    }
    const float dd = 1.0f / (2.0f * fmaxf(bq, 0.1f));
    const float q0 = b0*dd, q1 = b1*dd, q2 = b2*dd, q3 = b3*dd;
    const float qn = 1.0f / sqrtf(q0*q0 + q1*q1 + q2*q2 + q3*q3);
    const float aw = q0*qn, ax = q1*qn, ay = q2*qn, az = q3*qn;

    // ---- wait for this wave's DMA (+ dep/op) — per-wave, NOT a barrier ----
    asm volatile("s_waitcnt vmcnt(0)" ::: "memory");

    // gather this pixel's 12 floats from our wave's own LDS region
    const float4 r0 = sRaw[tid*3 + 0];   // raw[0..3]
    const float4 r1 = sRaw[tid*3 + 1];   // raw[4..7]
    const float4 r2 = sRaw[tid*3 + 2];   // raw[8..11]

    // ---- per-pixel work ----
    const int pix = g % HWc;
    const int h = pix / Wc;
    const int w = pix - h * Wc;

    const float x = (w + 0.5f) * (1.0f/Wc) + r0.x * (1.0f/Wc);
    const float y = (h + 0.5f) * (1.0f/Hc) + r0.y * (1.0f/Hc);

    float dc0 = K0*x + K1*y + K2;
    float dc1 = K3*x + K4*y + K5;
    float dc2 = K6*x + K7*y + K8;
    const float inl = rsqrtf(dc0*dc0 + dc1*dc1 + dc2*dc2);
    dc0 *= inl; dc1 *= inl; dc2 *= inl;

    const float dw0 = R0*dc0 + R1*dc1 + R2*dc2;
    const float dw1 = R3*dc0 + R4*dc1 + R5*dc2;
    const float dw2 = R6*dc0 + R7*dc1 + R8*dc2;

    const float sm  = dep * mult;
    const float sc0 = (SCALE_MIN_c + (SCALE_MAX_c - SCALE_MIN_c) / (1.0f + __expf(-r0.z))) * sm;
    const float sc1 = (SCALE_MIN_c + (SCALE_MAX_c - SCALE_MIN_c) / (1.0f + __expf(-r0.w))) * sm;
    const float sc2 = (SCALE_MIN_c + (SCALE_MAX_c - SCALE_MIN_c) / (1.0f + __expf(-r1.x))) * sm;

    // rotations: normalize raw[5:9] (xyzw) -> wxyz, quat-mul, direct f4 store
    const float rx = r1.y, ry = r1.z, rz = r1.w, rw = r2.x;
    const float rn = 1.0f / (sqrtf(rx*rx + ry*ry + rz*rz + rw*rw) + EPS_c);
    const float bwq = rw*rn, bxq = rx*rn, byq = ry*rn, bzq = rz*rn;
    float4 wq;
    wq.x = aw*bwq - ax*bxq - ay*byq - az*bzq;
    wq.y = aw*bxq + ax*bwq + ay*bzq - az*byq;
    wq.z = aw*byq - ax*bzq + ay*bwq + az*bxq;
    wq.w = aw*bzq + ax*byq - ay*bxq + az*bwq;
    reinterpret_cast<float4*>(out + ROT_OFF)[g] = wq;

    // opacity passthrough (coalesced dword)
    out[OPAC_OFF + g] = op;

    // ---- restage outputs into our OWN slot (no cross-thread hazard) ----
    // slot layout (12 floats): [m0 m1 m2 s0][s1 s2 h0 h1][h2 . . .]
    float4 A, Bv;
    A.x = O0 + dw0*dep;  A.y = O1 + dw1*dep;  A.z = O2 + dw2*dep;  A.w = sc0;
    Bv.x = sc1;  Bv.y = sc2;  Bv.z = r2.y;  Bv.w = r2.z;
    sRaw[tid*3 + 0] = A;
    sRaw[tid*3 + 1] = Bv;
    reinterpret_cast<float*>(sRaw)[tid*12 + 8] = r2.w;

    // ---- per-wave coalesced writeout: wave w emits its own 192 dwords/section
    // (intra-wave ds_write->ds_read ordering handled by lgkmcnt; lockstep wave)
    const float* sF = reinterpret_cast<const float*>(sRaw);
    float* outM = out + MEANS_OFF  + (size_t)blockIdx.x * 768;
    float* outS = out + SCALES_OFF + (size_t)blockIdx.x * 768;
    float* outH = out + HARM_OFF   + (size_t)blockIdx.x * 768;
    #pragma unroll
    for (int k = 0; k < 3; ++k) {
        const int off  = wv*192 + k*64 + lane;   // section dword this lane emits
        const int p    = off / 3;                // source pixel (inside our wave)
        const int c    = off - p*3;              // component
        const int base = p*12 + c;
        outM[off] = sF[base + 0];
        outS[off] = sF[base + 3];
        outH[off] = sF[base + 6];
    }
}

extern "C" void kernel_launch(void* const* d_in, const int* in_sizes, int n_in,
                              void* d_out, int out_size, void* d_ws, size_t ws_size,
                              hipStream_t stream) {
    const float* ext    = (const float*)d_in[0];
    const float* intr   = (const float*)d_in[1];
    const float* depths = (const float*)d_in[2];
    const float* opac   = (const float*)d_in[3];
    const float* raw    = (const float*)d_in[4];
    float* out = (float*)d_out;

    ga_kernel<<<TOTc / 256, 256, 0, stream>>>(ext, intr, depths, opac, raw, out);
}